// Round 10
// baseline (81.195 us; speedup 1.0000x reference)
//
#include <hip/hip_runtime.h>

#define HW2   96
#define NH    12
#define LPIX  (HW2*HW2)      // 9216
#define BATCH 4

typedef __attribute__((ext_vector_type(8))) short bf16x8;
typedef __attribute__((ext_vector_type(4))) float f32x4;

static __device__ __forceinline__ float bf2f(unsigned short u) {
  union { unsigned int i; float f; } v; v.i = ((unsigned int)u) << 16; return v.f;
}
static __device__ __forceinline__ unsigned short f2bf(float f) {
  union { float f; unsigned int i; } v; v.f = f;
  unsigned int r = v.i + 0x7FFF + ((v.i >> 16) & 1);   // round-nearest-even
  return (unsigned short)(r >> 16);
}

// ---- tiny: convert the three weight matrices to bf16 ----------------------
__global__ __launch_bounds__(256) void cvt_w_kernel(
    const float* __restrict__ Wq, const float* __restrict__ Wkv,
    const float* __restrict__ Wp,
    unsigned short* __restrict__ wqb, unsigned short* __restrict__ wkvb,
    unsigned short* __restrict__ wpb) {
  int i = blockIdx.x * 256 + threadIdx.x;
  if (i < 9216)       wqb[i]          = f2bf(Wq[i]);
  else if (i < 27648) wkvb[i - 9216]  = f2bf(Wkv[i - 9216]);
  else if (i < 64512) wpb[i - 27648]  = f2bf(Wp[i - 27648]);
}

// ---- fused Q+KV GEMM (round-8 passing body); HEAD-MAJOR epilogue ----------
// Qh[b][n][l][16], KVh[b][n][l][K16|V16].  GEMM row r: l=(r%18432)>>1,
// K/V parity = r&1 (even=K).  Scales folded here.
__global__ __launch_bounds__(256, 2) void qkv_gemm(
    const float* __restrict__ X,
    const unsigned short* __restrict__ wq, const unsigned short* __restrict__ wkv,
    const float* __restrict__ bq, const float* __restrict__ bkv,
    const float* __restrict__ fqr, const float* __restrict__ fkr,
    const float* __restrict__ fvr,
    unsigned short* __restrict__ Qh, unsigned short* __restrict__ KVh)
{
  __shared__ unsigned short lds[19456];
  unsigned short* xs  = lds;            // stride 120
  unsigned short* qo  = lds;            // stride 104 (64 x 96)
  unsigned short* kvo = lds + 6656;     // stride 200 (64 x 192)

  const int tid = threadIdx.x;
  const int r0  = blockIdx.x * 64;
  const int b   = r0 / 18432;
  const int lb  = (r0 % 18432) >> 1;

  const float4* xsrc = (const float4*)(X + (size_t)r0 * 96);
  #pragma unroll
  for (int it = 0; it < 6; it++) {
    int c = tid + it * 256;
    float4 v = xsrc[c];
    int row = c / 24, col = (c % 24) * 4;
    ushort4 p;
    p.x = f2bf(v.x); p.y = f2bf(v.y); p.z = f2bf(v.z); p.w = f2bf(v.w);
    *(ushort4*)&xs[row * 120 + col] = p;
  }
  __syncthreads();

  const int lane = tid & 63, w = tid >> 6;
  const int col  = lane & 15;
  const int koff = (lane >> 4) * 8;
  const int arow = 16 * w + (lane & 15);
  const int rloc = 16 * w + 4 * (lane >> 4);

  bf16x8 af0 = *(const bf16x8*)&xs[arow * 120 + koff];
  bf16x8 af1 = *(const bf16x8*)&xs[arow * 120 + koff + 32];
  bf16x8 af2 = *(const bf16x8*)&xs[arow * 120 + koff + 64];
  __syncthreads();                             // xs dead; reuse as qo/kvo

  const float fqr0 = fqr[0] * 0.07216878364870322f;
  const float fkr0 = fkr[0], fvr0 = fvr[0];

  #pragma unroll
  for (int g = 0; g < 3; g++) {
    bf16x8 bw0[6], bw1[6], bw2[6];
    #pragma unroll
    for (int j = 0; j < 6; j++) {
      int nt = g * 6 + j;
      const unsigned short* wrow = (nt < 6)
          ? wq  + (size_t)(nt * 16 + col) * 96 + koff
          : wkv + (size_t)((nt - 6) * 16 + col) * 96 + koff;
      bw0[j] = *(const bf16x8*)(wrow);
      bw1[j] = *(const bf16x8*)(wrow + 32);
      bw2[j] = *(const bf16x8*)(wrow + 64);
    }
    asm volatile("" ::: "memory");

    #pragma unroll
    for (int j = 0; j < 6; j++) {
      int nt = g * 6 + j;
      f32x4 acc = {0.f, 0.f, 0.f, 0.f};
      acc = __builtin_amdgcn_mfma_f32_16x16x32_bf16(af0, bw0[j], acc, 0, 0, 0);
      acc = __builtin_amdgcn_mfma_f32_16x16x32_bf16(af1, bw1[j], acc, 0, 0, 0);
      acc = __builtin_amdgcn_mfma_f32_16x16x32_bf16(af2, bw2[j], acc, 0, 0, 0);

      if (nt < 6) {
        int u = nt * 16 + col;
        float bias = bq[u];
        #pragma unroll
        for (int i = 0; i < 4; i++)
          qo[(rloc + i) * 104 + u] = f2bf((acc[i] + bias) * fqr0);
      } else {
        int u = (nt - 6) * 16 + col;
        float bias = bkv[u];
        #pragma unroll
        for (int i = 0; i < 4; i++) {
          float s = (i & 1) ? fvr0 : fkr0;     // row parity: even=K, odd=V
          kvo[(rloc + i) * 200 + u] = f2bf((acc[i] + bias) * s);
        }
      }
    }
  }
  __syncthreads();

  // Q: 768 chunks -> Qh[b][n][lb+l_loc][half]
  #pragma unroll
  for (int it = 0; it < 3; it++) {
    int m = tid + it * 256;
    int n = m >> 6, rem = m & 63;
    int l_loc = rem >> 1, half = (m & 1) * 8;
    int srow = 2 * l_loc + (n >= 6);
    int scol = (n % 6) * 16 + half;
    unsigned short* dst = Qh + (size_t)b * 1769472 + (size_t)n * 147456
                        + (size_t)(lb + l_loc) * 16 + half;
    *(uint4*)dst = *(const uint4*)&qo[srow * 104 + scol];
  }
  // KV: 1536 chunks -> KVh[b][n][lb+l_loc][kv*16+half]
  #pragma unroll
  for (int it = 0; it < 6; it++) {
    int m = tid + it * 256;
    int n = m >> 7, rem = m & 127;
    int l_loc = rem >> 2;
    int kv = (m >> 1) & 1, half = (m & 1) * 8;
    int srow = 2 * l_loc + kv;
    int scol = n * 16 + half;
    unsigned short* dst = KVh + (size_t)b * 3538944 + (size_t)n * 294912
                        + (size_t)(lb + l_loc) * 32 + kv * 16 + half;
    *(uint4*)dst = *(const uint4*)&kvo[srow * 200 + scol];
  }
}

// ---- attention: per-(batch,head) 16x32 pixel tile, KV halo in LDS ---------
// Block stages the 18x34 halo (each halo row = 34*64B contiguous) into LDS
// padded to 80B/pixel (16B-aligned, bank-uniform).  Each thread: 1 pixel;
// 9-neighbor K/V come from LDS, not global.
__global__ __launch_bounds__(512) void attn_kernel(
    const unsigned short* __restrict__ Qh, const unsigned short* __restrict__ KVh,
    unsigned short* __restrict__ O2h)
{
  __shared__ unsigned short kvs[18 * 34 * 40];   // 48,960 B
  const int tid = threadIdx.x;
  const int bgn  = blockIdx.x / 18;              // b*12 + n
  const int tile = blockIdx.x % 18;
  const int h0 = (tile / 3) * 16, w0 = (tile % 3) * 32;

  const unsigned short* kvbase = KVh + (size_t)bgn * (LPIX * 32);

  // stage halo: 612 pixels x 4 chunks(16B) = 2448 chunks
  #pragma unroll
  for (int it = 0; it < 5; it++) {
    int c = tid + it * 512;
    if (c < 2448) {
      int p = c >> 2, part = (c & 3) * 8;
      int hr = p / 34, wc = p - hr * 34;
      int hh = min(max(h0 - 1 + hr, 0), HW2 - 1);
      int ww = min(max(w0 - 1 + wc, 0), HW2 - 1);
      *(uint4*)&kvs[p * 40 + part] =
          *(const uint4*)(kvbase + (size_t)(hh * HW2 + ww) * 32 + part);
    }
  }
  __syncthreads();

  const int pr = tid >> 5, pc = tid & 31;
  const int h = h0 + pr, w = w0 + pc;
  const int l = h * HW2 + w;

  const unsigned short* qp = Qh + ((size_t)bgn * LPIX + l) * 16;
  uint4 qA = *(const uint4*)(qp);
  uint4 qB = *(const uint4*)(qp + 8);
  float q[16];
  {
    const unsigned short* qs = (const unsigned short*)&qA;
    #pragma unroll
    for (int j = 0; j < 8; j++) q[j] = bf2f(qs[j]);
    qs = (const unsigned short*)&qB;
    #pragma unroll
    for (int j = 0; j < 8; j++) q[8 + j] = bf2f(qs[j]);
  }

  float sc[9];
  bool  okk[9];
  #pragma unroll
  for (int kk = 0; kk < 9; kk++) {
    int dr = kk / 3, dc = kk % 3;
    okk[kk] = ((unsigned)(h + dr - 1) < (unsigned)HW2) &&
              ((unsigned)(w + dc - 1) < (unsigned)HW2);
    const unsigned short* kp = &kvs[((pr + dr) * 34 + pc + dc) * 40];
    uint4 k0 = *(const uint4*)(kp);
    uint4 k1 = *(const uint4*)(kp + 8);
    float s = 0.f;
    const unsigned short* kd = (const unsigned short*)&k0;
    #pragma unroll
    for (int j = 0; j < 8; j++) s = fmaf(q[j], bf2f(kd[j]), s);
    kd = (const unsigned short*)&k1;
    #pragma unroll
    for (int j = 0; j < 8; j++) s = fmaf(q[8 + j], bf2f(kd[j]), s);
    sc[kk] = okk[kk] ? s : 0.f;                  // zero-padded score semantics
  }

  float m = sc[0];
  #pragma unroll
  for (int kk = 1; kk < 9; kk++) m = fmaxf(m, sc[kk]);
  float ssum = 0.f;
  #pragma unroll
  for (int kk = 0; kk < 9; kk++) {
    float e = __expf(sc[kk] - m);
    sc[kk] = e;
    ssum += e;                                   // invalid ones DO count (pad=0)
  }

  float acc[16];
  #pragma unroll
  for (int j = 0; j < 16; j++) acc[j] = 0.f;
  #pragma unroll
  for (int kk = 0; kk < 9; kk++) {
    int dr = kk / 3, dc = kk % 3;
    const unsigned short* vp = &kvs[((pr + dr) * 34 + pc + dc) * 40 + 16];
    uint4 v0 = *(const uint4*)(vp);
    uint4 v1 = *(const uint4*)(vp + 8);
    float wgt = okk[kk] ? sc[kk] : 0.f;          // V of padded neighbors = 0
    const unsigned short* vd = (const unsigned short*)&v0;
    #pragma unroll
    for (int j = 0; j < 8; j++) acc[j] = fmaf(wgt, bf2f(vd[j]), acc[j]);
    vd = (const unsigned short*)&v1;
    #pragma unroll
    for (int j = 0; j < 8; j++) acc[8 + j] = fmaf(wgt, bf2f(vd[j]), acc[8 + j]);
  }
  float rinv = 1.f / ssum;
  unsigned short od[16];
  #pragma unroll
  for (int j = 0; j < 16; j++) od[j] = f2bf(acc[j] * rinv);
  unsigned short* op = O2h + ((size_t)bgn * LPIX + l) * 16;
  *(uint4*)(op)     = *(uint4*)&od[0];
  *(uint4*)(op + 8) = *(uint4*)&od[8];
}

// ---- proj GEMM: A = out2 head-major -> staged 64x192 tile -> MFMA ---------
__global__ __launch_bounds__(256) void proj_gemm(
    const unsigned short* __restrict__ A, const unsigned short* __restrict__ wp,
    const float* __restrict__ bp, float* __restrict__ Out)
{
  __shared__ unsigned short xs[64 * 200];
  const int tid = threadIdx.x;
  const int l0g = blockIdx.x * 64;               // global (b,l) row base
  const int b   = l0g / LPIX;
  const int l0  = l0g % LPIX;

  // stage: 12 heads x 64 rows x 2 chunks; contiguous 2KB run per head
  #pragma unroll
  for (int it = 0; it < 6; it++) {
    int m = tid + it * 256;
    int n = m >> 7, rem = m & 127;
    int row = rem >> 1, half = (m & 1) * 8;
    const unsigned short* src = A + ((size_t)(b * NH + n) * LPIX + l0 + row) * 16 + half;
    *(uint4*)&xs[row * 200 + n * 16 + half] = *(const uint4*)src;
  }
  __syncthreads();

  const int lane = tid & 63, w = tid >> 6;
  const int col  = lane & 15;
  const int koff = (lane >> 4) * 8;
  const int arow = 16 * w + (lane & 15);
  const int rbase = l0g + 16 * w + 4 * (lane >> 4);

  bf16x8 af[6];
  #pragma unroll
  for (int kt = 0; kt < 6; kt++)
    af[kt] = *(const bf16x8*)&xs[arow * 200 + koff + kt * 32];

  #pragma unroll
  for (int nt = 0; nt < 12; nt++) {
    const unsigned short* wrow = wp + (size_t)(nt * 16 + col) * 192 + koff;
    f32x4 acc = {0.f, 0.f, 0.f, 0.f};
    #pragma unroll
    for (int kt = 0; kt < 6; kt++) {
      bf16x8 bfr = *(const bf16x8*)(wrow + kt * 32);
      acc = __builtin_amdgcn_mfma_f32_16x16x32_bf16(af[kt], bfr, acc, 0, 0, 0);
    }
    int u = nt * 16 + col;
    float bias = bp[u];
    #pragma unroll
    for (int i = 0; i < 4; i++)
      Out[(size_t)(rbase + i) * 192 + u] = acc[i] + bias;
  }
}

extern "C" void kernel_launch(void* const* d_in, const int* in_sizes, int n_in,
                              void* d_out, int out_size, void* d_ws, size_t ws_size,
                              hipStream_t stream) {
  const float* x   = (const float*)d_in[0];
  const float* Wq  = (const float*)d_in[1];
  const float* bq  = (const float*)d_in[2];
  const float* Wkv = (const float*)d_in[3];
  const float* bkv = (const float*)d_in[4];
  const float* Wp  = (const float*)d_in[5];
  const float* bp  = (const float*)d_in[6];
  const float* fqr = (const float*)d_in[7];
  const float* fkr = (const float*)d_in[8];
  const float* fvr = (const float*)d_in[9];

  char* ws = (char*)d_ws;
  unsigned short* Qh   = (unsigned short*)ws;                 // 14,155,776 B
  unsigned short* KVh  = (unsigned short*)(ws + 14155776);    // 28,311,552 B
  unsigned short* O2h  = (unsigned short*)(ws + 42467328);    // 14,155,776 B
  unsigned short* wqb  = (unsigned short*)(ws + 56623104);
  unsigned short* wkvb = (unsigned short*)(ws + 56641536);
  unsigned short* wpb  = (unsigned short*)(ws + 56678400);

  cvt_w_kernel<<<dim3(252), dim3(256), 0, stream>>>(Wq, Wkv, Wp, wqb, wkvb, wpb);

  qkv_gemm<<<dim3(1152), dim3(256), 0, stream>>>(
      x, wqb, wkvb, bq, bkv, fqr, fkr, fvr, Qh, KVh);

  attn_kernel<<<dim3(864), dim3(512), 0, stream>>>(Qh, KVh, O2h);

  proj_gemm<<<dim3(576), dim3(256), 0, stream>>>(O2h, wpb, bp, (float*)d_out);
}

// Round 11
// 74.613 us; speedup vs baseline: 1.0882x; 1.0882x over previous
//
#include <hip/hip_runtime.h>

#define HW2   96
#define NH    12
#define LPIX  (HW2*HW2)      // 9216
#define BATCH 4

typedef __attribute__((ext_vector_type(8))) short bf16x8;
typedef __attribute__((ext_vector_type(4))) float f32x4;

static __device__ __forceinline__ float bf2f(unsigned short u) {
  union { unsigned int i; float f; } v; v.i = ((unsigned int)u) << 16; return v.f;
}
static __device__ __forceinline__ unsigned short f2bf(float f) {
  union { float f; unsigned int i; } v; v.f = f;
  unsigned int r = v.i + 0x7FFF + ((v.i >> 16) & 1);   // round-nearest-even
  return (unsigned short)(r >> 16);
}

// ---- tiny: convert the three weight matrices to bf16 ----------------------
__global__ __launch_bounds__(256) void cvt_w_kernel(
    const float* __restrict__ Wq, const float* __restrict__ Wkv,
    const float* __restrict__ Wp,
    unsigned short* __restrict__ wqb, unsigned short* __restrict__ wkvb,
    unsigned short* __restrict__ wpb) {
  int i = blockIdx.x * 256 + threadIdx.x;
  if (i < 9216)       wqb[i]          = f2bf(Wq[i]);
  else if (i < 27648) wkvb[i - 9216]  = f2bf(Wkv[i - 9216]);
  else if (i < 64512) wpb[i - 27648]  = f2bf(Wp[i - 27648]);
}

// ---- fused Q+KV GEMM, BARRIER-FREE: A-frags direct from global (in-reg
// fp32->bf16), epilogue stores direct to global. No LDS, no __syncthreads:
// waves run independently so memory latency is hidden by occupancy.
__global__ __launch_bounds__(256, 4) void qkv_gemm(
    const float* __restrict__ X,
    const unsigned short* __restrict__ wq, const unsigned short* __restrict__ wkv,
    const float* __restrict__ bq, const float* __restrict__ bkv,
    const float* __restrict__ fqr, const float* __restrict__ fkr,
    const float* __restrict__ fvr,
    unsigned short* __restrict__ Qb, unsigned short* __restrict__ KVb)
{
  const int tid  = threadIdx.x;
  const int r0   = blockIdx.x * 64;
  const int lane = tid & 63, w = tid >> 6;
  const int col  = lane & 15;
  const int koff = (lane >> 4) * 8;
  const int arow = r0 + 16 * w + (lane & 15);
  const int rbase = r0 + 16 * w + 4 * (lane >> 4);

  // A-fragments: lane reads x[arow][koff + {0..7, 32..39, 64..71}] fp32
  const float* xr = X + (size_t)arow * 96;
  float xv[24];
  *(float4*)&xv[0]  = *(const float4*)(xr + koff);
  *(float4*)&xv[4]  = *(const float4*)(xr + koff + 4);
  *(float4*)&xv[8]  = *(const float4*)(xr + koff + 32);
  *(float4*)&xv[12] = *(const float4*)(xr + koff + 36);
  *(float4*)&xv[16] = *(const float4*)(xr + koff + 64);
  *(float4*)&xv[20] = *(const float4*)(xr + koff + 68);
  unsigned short au[24];
  #pragma unroll
  for (int j = 0; j < 24; j++) au[j] = f2bf(xv[j]);
  bf16x8 af0 = *(const bf16x8*)&au[0];
  bf16x8 af1 = *(const bf16x8*)&au[8];
  bf16x8 af2 = *(const bf16x8*)&au[16];

  const float fqr0 = fqr[0] * 0.07216878364870322f;
  const float fkr0 = fkr[0], fvr0 = fvr[0];

  // 6 groups x 3 output tiles; 9 W loads prefetched per group (fence-held)
  #pragma unroll
  for (int g = 0; g < 6; g++) {
    bf16x8 bw0[3], bw1[3], bw2[3];
    #pragma unroll
    for (int j = 0; j < 3; j++) {
      int nt = g * 3 + j;
      const unsigned short* wrow = (nt < 6)
          ? wq  + (size_t)(nt * 16 + col) * 96 + koff
          : wkv + (size_t)((nt - 6) * 16 + col) * 96 + koff;
      bw0[j] = *(const bf16x8*)(wrow);
      bw1[j] = *(const bf16x8*)(wrow + 32);
      bw2[j] = *(const bf16x8*)(wrow + 64);
    }
    asm volatile("" ::: "memory");             // keep the 9 loads in flight

    #pragma unroll
    for (int j = 0; j < 3; j++) {
      int nt = g * 3 + j;
      f32x4 acc = {0.f, 0.f, 0.f, 0.f};
      acc = __builtin_amdgcn_mfma_f32_16x16x32_bf16(af0, bw0[j], acc, 0, 0, 0);
      acc = __builtin_amdgcn_mfma_f32_16x16x32_bf16(af1, bw1[j], acc, 0, 0, 0);
      acc = __builtin_amdgcn_mfma_f32_16x16x32_bf16(af2, bw2[j], acc, 0, 0, 0);

      if (nt < 6) {
        int u = nt * 16 + col;
        float bias = bq[u];
        #pragma unroll
        for (int i = 0; i < 4; i++)
          Qb[(size_t)(rbase + i) * 96 + u] = f2bf((acc[i] + bias) * fqr0);
      } else {
        int u = (nt - 6) * 16 + col;
        float bias = bkv[u];
        #pragma unroll
        for (int i = 0; i < 4; i++) {
          float s = (i & 1) ? fvr0 : fkr0;     // row parity: even=K, odd=V
          KVb[(size_t)(rbase + i) * 192 + u] = f2bf((acc[i] + bias) * s);
        }
      }
    }
  }
}

// ---- fused attention + proj (round-8 passing version, verbatim) -----------
__global__ __launch_bounds__(384, 1) void attnproj_kernel(
    const unsigned short* __restrict__ Qb, const unsigned short* __restrict__ KVb,
    const unsigned short* __restrict__ wp, const float* __restrict__ bp,
    float* __restrict__ Out)
{
  __shared__ unsigned short s_out[32 * 204];
  const int tid = threadIdx.x;
  // XCD-chunked swizzle: 144 consecutive blocks (48 image rows) per XCD.
  const int bid = (blockIdx.x & 7) * 144 + (blockIdx.x >> 3);
  const int bl0 = bid * 32;

  {
    const int n  = tid % NH;
    const int pl = tid / NH;                   // 0..31
    const int bl = bl0 + pl;
    const int l  = bl % LPIX;
    const int b  = bl / LPIX;
    const int h2 = l / HW2, w2 = l - h2 * HW2;

    const unsigned short* qp = Qb + (size_t)bl * 192 + n * 16;
    uint4 qA = *(const uint4*)(qp);
    uint4 qB = *(const uint4*)(qp + 8);

    const unsigned short* kvb = KVb + (size_t)b * (LPIX * 384) + n * 16;

    // ---- issue ALL neighbor loads, then fence ----
    int  nbo[9];
    bool okk[9];
    uint4 kA[9], kB[9], vA[9], vB[9];
    #pragma unroll
    for (int kk = 0; kk < 9; kk++) {
      int hh = h2 + kk / 3 - 1;
      int ww = w2 + kk % 3 - 1;
      okk[kk] = ((unsigned)hh < (unsigned)HW2) && ((unsigned)ww < (unsigned)HW2);
      int hc = min(max(hh, 0), HW2 - 1);
      int wc = min(max(ww, 0), HW2 - 1);
      nbo[kk] = (hc * HW2 + wc) * 384;
      const unsigned short* kp = kvb + nbo[kk];
      kA[kk] = *(const uint4*)(kp);
      kB[kk] = *(const uint4*)(kp + 8);
    }
    #pragma unroll
    for (int kk = 0; kk < 9; kk++) {
      const unsigned short* vp = kvb + nbo[kk] + 192;
      vA[kk] = *(const uint4*)(vp);
      vB[kk] = *(const uint4*)(vp + 8);
    }
    asm volatile("" ::: "memory");             // loads in flight together

    float q[16];
    {
      const unsigned short* qs = (const unsigned short*)&qA;
      #pragma unroll
      for (int j = 0; j < 8; j++) q[j] = bf2f(qs[j]);
      qs = (const unsigned short*)&qB;
      #pragma unroll
      for (int j = 0; j < 8; j++) q[8 + j] = bf2f(qs[j]);
    }

    float sc[9];
    #pragma unroll
    for (int kk = 0; kk < 9; kk++) {
      float s = 0.f;
      const unsigned short* kd = (const unsigned short*)&kA[kk];
      #pragma unroll
      for (int j = 0; j < 8; j++) s = fmaf(q[j], bf2f(kd[j]), s);
      kd = (const unsigned short*)&kB[kk];
      #pragma unroll
      for (int j = 0; j < 8; j++) s = fmaf(q[8 + j], bf2f(kd[j]), s);
      sc[kk] = okk[kk] ? s : 0.f;
    }

    float m = sc[0];
    #pragma unroll
    for (int kk = 1; kk < 9; kk++) m = fmaxf(m, sc[kk]);
    float ssum = 0.f;
    #pragma unroll
    for (int kk = 0; kk < 9; kk++) {
      float e = __expf(sc[kk] - m);
      sc[kk] = e;
      ssum += e;
    }

    float acc[16];
    #pragma unroll
    for (int j = 0; j < 16; j++) acc[j] = 0.f;
    #pragma unroll
    for (int kk = 0; kk < 9; kk++) {
      float wgt = okk[kk] ? sc[kk] : 0.f;
      const unsigned short* vd = (const unsigned short*)&vA[kk];
      #pragma unroll
      for (int j = 0; j < 8; j++) acc[j] = fmaf(wgt, bf2f(vd[j]), acc[j]);
      vd = (const unsigned short*)&vB[kk];
      #pragma unroll
      for (int j = 0; j < 8; j++) acc[8 + j] = fmaf(wgt, bf2f(vd[j]), acc[8 + j]);
    }
    float rinv = 1.f / ssum;
    unsigned short od[16];
    #pragma unroll
    for (int j = 0; j < 16; j++) od[j] = f2bf(acc[j] * rinv);
    unsigned short* op = s_out + pl * 204 + n * 16;
    *(uint4*)(op)     = *(uint4*)&od[0];
    *(uint4*)(op + 8) = *(uint4*)&od[8];
  }
  __syncthreads();

  // ---- proj phase: (32x192 bf16 LDS) x Wp^T + bp -> Out fp32, 6 waves ----
  const int lane = tid & 63, w = tid >> 6;     // 6 waves
  const int wr = w & 1, wh = w >> 1;           // wr: row half, wh: 0..2
  const int col  = lane & 15;
  const int koff = (lane >> 4) * 8;
  const int arow = 16 * wr + (lane & 15);
  const int rbase = bl0 + 16 * wr + 4 * (lane >> 4);

  bf16x8 af[6];
  #pragma unroll
  for (int kt = 0; kt < 6; kt++)
    af[kt] = *(const bf16x8*)&s_out[arow * 204 + koff + kt * 32];

  // preissue all 24 W loads for this wave's 4 output tiles
  bf16x8 bw[4][6];
  #pragma unroll
  for (int t4 = 0; t4 < 4; t4++) {
    int nt = wh * 4 + t4;
    const unsigned short* wrow = wp + (size_t)(nt * 16 + col) * 192 + koff;
    #pragma unroll
    for (int kt = 0; kt < 6; kt++)
      bw[t4][kt] = *(const bf16x8*)(wrow + kt * 32);
  }
  asm volatile("" ::: "memory");

  #pragma unroll
  for (int t4 = 0; t4 < 4; t4++) {
    int nt = wh * 4 + t4;
    f32x4 acc = {0.f, 0.f, 0.f, 0.f};
    #pragma unroll
    for (int kt = 0; kt < 6; kt++)
      acc = __builtin_amdgcn_mfma_f32_16x16x32_bf16(af[kt], bw[t4][kt], acc, 0, 0, 0);
    int u = nt * 16 + col;
    float bias = bp[u];
    #pragma unroll
    for (int i = 0; i < 4; i++)
      Out[(size_t)(rbase + i) * 192 + u] = acc[i] + bias;
  }
}

extern "C" void kernel_launch(void* const* d_in, const int* in_sizes, int n_in,
                              void* d_out, int out_size, void* d_ws, size_t ws_size,
                              hipStream_t stream) {
  const float* x   = (const float*)d_in[0];
  const float* Wq  = (const float*)d_in[1];
  const float* bq  = (const float*)d_in[2];
  const float* Wkv = (const float*)d_in[3];
  const float* bkv = (const float*)d_in[4];
  const float* Wp  = (const float*)d_in[5];
  const float* bp  = (const float*)d_in[6];
  const float* fqr = (const float*)d_in[7];
  const float* fkr = (const float*)d_in[8];
  const float* fvr = (const float*)d_in[9];

  char* ws = (char*)d_ws;
  unsigned short* Qb   = (unsigned short*)ws;                 // 14,155,776 B
  unsigned short* KVb  = (unsigned short*)(ws + 14155776);    // 28,311,552 B
  unsigned short* wqb  = (unsigned short*)(ws + 42467328);
  unsigned short* wkvb = (unsigned short*)(ws + 42485760);
  unsigned short* wpb  = (unsigned short*)(ws + 42522624);

  cvt_w_kernel<<<dim3(252), dim3(256), 0, stream>>>(Wq, Wkv, Wp, wqb, wkvb, wpb);

  qkv_gemm<<<dim3(1152), dim3(256), 0, stream>>>(
      x, wqb, wkvb, bq, bkv, fqr, fkr, fvr, Qb, KVb);

  attnproj_kernel<<<dim3(1152), dim3(384), 0, stream>>>(
      Qb, KVb, wpb, bp, (float*)d_out);
}

// Round 12
// 66.195 us; speedup vs baseline: 1.2266x; 1.1272x over previous
//
#include <hip/hip_runtime.h>

#define HW2   96
#define NH    12
#define LPIX  (HW2*HW2)      // 9216
#define BATCH 4

typedef __attribute__((ext_vector_type(8))) short bf16x8;
typedef __attribute__((ext_vector_type(4))) float f32x4;

static __device__ __forceinline__ float bf2f(unsigned short u) {
  union { unsigned int i; float f; } v; v.i = ((unsigned int)u) << 16; return v.f;
}
static __device__ __forceinline__ unsigned short f2bf(float f) {
  union { float f; unsigned int i; } v; v.f = f;
  unsigned int r = v.i + 0x7FFF + ((v.i >> 16) & 1);   // round-nearest-even
  return (unsigned short)(r >> 16);
}

// ---- tiny: convert the three weight matrices to bf16 ----------------------
__global__ __launch_bounds__(256) void cvt_w_kernel(
    const float* __restrict__ Wq, const float* __restrict__ Wkv,
    const float* __restrict__ Wp,
    unsigned short* __restrict__ wqb, unsigned short* __restrict__ wkvb,
    unsigned short* __restrict__ wpb) {
  int i = blockIdx.x * 256 + threadIdx.x;
  if (i < 9216)       wqb[i]          = f2bf(Wq[i]);
  else if (i < 27648) wkvb[i - 9216]  = f2bf(Wkv[i - 9216]);
  else if (i < 64512) wpb[i - 27648]  = f2bf(Wp[i - 27648]);
}

// ---- fused Q+KV GEMM, barrier-free, ILP=2: block owns TWO 64-row tiles.
// The 9 W loads per group feed 6 MFMA (both tiles) -> latency amortized 2x,
// plus two independent accumulate/store chains per thread.
__global__ __launch_bounds__(256) void qkv_gemm(
    const float* __restrict__ X,
    const unsigned short* __restrict__ wq, const unsigned short* __restrict__ wkv,
    const float* __restrict__ bq, const float* __restrict__ bkv,
    const float* __restrict__ fqr, const float* __restrict__ fkr,
    const float* __restrict__ fvr,
    unsigned short* __restrict__ Qb, unsigned short* __restrict__ KVb)
{
  const int tid  = threadIdx.x;
  const int r0   = blockIdx.x * 128;
  const int lane = tid & 63, w = tid >> 6;
  const int col  = lane & 15;
  const int koff = (lane >> 4) * 8;
  const int arow0 = r0 + 16 * w + (lane & 15);
  const int rb0   = r0 + 16 * w + 4 * (lane >> 4);

  // A-fragments for both tiles (rows arow0 and arow0+64)
  bf16x8 af[2][3];
  #pragma unroll
  for (int t = 0; t < 2; t++) {
    const float* xr = X + (size_t)(arow0 + 64 * t) * 96;
    float xv[24];
    *(float4*)&xv[0]  = *(const float4*)(xr + koff);
    *(float4*)&xv[4]  = *(const float4*)(xr + koff + 4);
    *(float4*)&xv[8]  = *(const float4*)(xr + koff + 32);
    *(float4*)&xv[12] = *(const float4*)(xr + koff + 36);
    *(float4*)&xv[16] = *(const float4*)(xr + koff + 64);
    *(float4*)&xv[20] = *(const float4*)(xr + koff + 68);
    unsigned short au[24];
    #pragma unroll
    for (int j = 0; j < 24; j++) au[j] = f2bf(xv[j]);
    af[t][0] = *(const bf16x8*)&au[0];
    af[t][1] = *(const bf16x8*)&au[8];
    af[t][2] = *(const bf16x8*)&au[16];
  }

  const float fqr0 = fqr[0] * 0.07216878364870322f;
  const float fkr0 = fkr[0], fvr0 = fvr[0];

  #pragma unroll
  for (int g = 0; g < 6; g++) {
    bf16x8 bw0[3], bw1[3], bw2[3];
    #pragma unroll
    for (int j = 0; j < 3; j++) {
      int nt = g * 3 + j;
      const unsigned short* wrow = (nt < 6)
          ? wq  + (size_t)(nt * 16 + col) * 96 + koff
          : wkv + (size_t)((nt - 6) * 16 + col) * 96 + koff;
      bw0[j] = *(const bf16x8*)(wrow);
      bw1[j] = *(const bf16x8*)(wrow + 32);
      bw2[j] = *(const bf16x8*)(wrow + 64);
    }
    asm volatile("" ::: "memory");             // keep the 9 loads in flight

    #pragma unroll
    for (int j = 0; j < 3; j++) {
      int nt = g * 3 + j;
      f32x4 acc[2];
      #pragma unroll
      for (int t = 0; t < 2; t++) {
        f32x4 a = {0.f, 0.f, 0.f, 0.f};
        a = __builtin_amdgcn_mfma_f32_16x16x32_bf16(af[t][0], bw0[j], a, 0, 0, 0);
        a = __builtin_amdgcn_mfma_f32_16x16x32_bf16(af[t][1], bw1[j], a, 0, 0, 0);
        a = __builtin_amdgcn_mfma_f32_16x16x32_bf16(af[t][2], bw2[j], a, 0, 0, 0);
        acc[t] = a;
      }

      if (nt < 6) {
        int u = nt * 16 + col;
        float bias = bq[u];
        #pragma unroll
        for (int t = 0; t < 2; t++)
          #pragma unroll
          for (int i = 0; i < 4; i++)
            Qb[(size_t)(rb0 + 64 * t + i) * 96 + u] = f2bf((acc[t][i] + bias) * fqr0);
      } else {
        int u = (nt - 6) * 16 + col;
        float bias = bkv[u];
        #pragma unroll
        for (int t = 0; t < 2; t++)
          #pragma unroll
          for (int i = 0; i < 4; i++) {
            float s = (i & 1) ? fvr0 : fkr0;   // row parity: even=K, odd=V
            KVb[(size_t)(rb0 + 64 * t + i) * 192 + u] = f2bf((acc[t][i] + bias) * s);
          }
      }
    }
  }
}

// ---- fused attention + proj, ILP=2: block = 64 pixels, 384 threads, each
// thread runs TWO independent (pixel,head) tasks with batched load phases.
__global__ __launch_bounds__(384) void attnproj_kernel(
    const unsigned short* __restrict__ Qb, const unsigned short* __restrict__ KVb,
    const unsigned short* __restrict__ wp, const float* __restrict__ bp,
    float* __restrict__ Out)
{
  __shared__ unsigned short s_out[64 * 204];
  const int tid = threadIdx.x;
  // XCD-chunked swizzle (576 blocks, 72/XCD): halo rows share an XCD L2.
  const int bid = (blockIdx.x & 7) * 72 + (blockIdx.x >> 3);
  const int bl0 = bid * 64;

  {
    const int n   = tid % NH;
    const int pl0 = tid / NH;                  // 0..31
    const int b   = bl0 / LPIX;                // block never straddles batch
    const unsigned short* kvb = KVb + (size_t)b * (LPIX * 384) + n * 16;

    int  nbo[2][9];
    bool okk[2][9];
    uint4 qA[2], qB[2], kA[2][9], kB[2][9];

    // ---- batched K+Q issue for BOTH tasks, then fence ----
    #pragma unroll
    for (int t = 0; t < 2; t++) {
      int pl = pl0 + 32 * t;
      int l  = (bl0 + pl) % LPIX;
      int h2 = l / HW2, w2 = l - h2 * HW2;
      #pragma unroll
      for (int kk = 0; kk < 9; kk++) {
        int hh = h2 + kk / 3 - 1;
        int ww = w2 + kk % 3 - 1;
        okk[t][kk] = ((unsigned)hh < (unsigned)HW2) && ((unsigned)ww < (unsigned)HW2);
        int hc = min(max(hh, 0), HW2 - 1);
        int wc = min(max(ww, 0), HW2 - 1);
        nbo[t][kk] = (hc * HW2 + wc) * 384;
        const unsigned short* kp = kvb + nbo[t][kk];
        kA[t][kk] = *(const uint4*)(kp);
        kB[t][kk] = *(const uint4*)(kp + 8);
      }
      const unsigned short* qp = Qb + (size_t)(bl0 + pl) * 192 + n * 16;
      qA[t] = *(const uint4*)(qp);
      qB[t] = *(const uint4*)(qp + 8);
    }
    asm volatile("" ::: "memory");

    // ---- scores for both tasks ----
    float sc[2][9];
    #pragma unroll
    for (int t = 0; t < 2; t++) {
      float q[16];
      const unsigned short* qs = (const unsigned short*)&qA[t];
      #pragma unroll
      for (int j = 0; j < 8; j++) q[j] = bf2f(qs[j]);
      qs = (const unsigned short*)&qB[t];
      #pragma unroll
      for (int j = 0; j < 8; j++) q[8 + j] = bf2f(qs[j]);
      #pragma unroll
      for (int kk = 0; kk < 9; kk++) {
        float s = 0.f;
        const unsigned short* kd = (const unsigned short*)&kA[t][kk];
        #pragma unroll
        for (int j = 0; j < 8; j++) s = fmaf(q[j], bf2f(kd[j]), s);
        kd = (const unsigned short*)&kB[t][kk];
        #pragma unroll
        for (int j = 0; j < 8; j++) s = fmaf(q[8 + j], bf2f(kd[j]), s);
        sc[t][kk] = okk[t][kk] ? s : 0.f;
      }
    }

    // ---- batched V issue for both tasks, then fence ----
    uint4 vA[2][9], vB[2][9];
    #pragma unroll
    for (int t = 0; t < 2; t++)
      #pragma unroll
      for (int kk = 0; kk < 9; kk++) {
        const unsigned short* vp = kvb + nbo[t][kk] + 192;
        vA[t][kk] = *(const uint4*)(vp);
        vB[t][kk] = *(const uint4*)(vp + 8);
      }
    asm volatile("" ::: "memory");

    // ---- softmax + PV + LDS store per task ----
    #pragma unroll
    for (int t = 0; t < 2; t++) {
      float m = sc[t][0];
      #pragma unroll
      for (int kk = 1; kk < 9; kk++) m = fmaxf(m, sc[t][kk]);
      float ssum = 0.f;
      #pragma unroll
      for (int kk = 0; kk < 9; kk++) {
        float e = __expf(sc[t][kk] - m);
        sc[t][kk] = e;
        ssum += e;
      }
      float acc[16];
      #pragma unroll
      for (int j = 0; j < 16; j++) acc[j] = 0.f;
      #pragma unroll
      for (int kk = 0; kk < 9; kk++) {
        float wgt = okk[t][kk] ? sc[t][kk] : 0.f;
        const unsigned short* vd = (const unsigned short*)&vA[t][kk];
        #pragma unroll
        for (int j = 0; j < 8; j++) acc[j] = fmaf(wgt, bf2f(vd[j]), acc[j]);
        vd = (const unsigned short*)&vB[t][kk];
        #pragma unroll
        for (int j = 0; j < 8; j++) acc[8 + j] = fmaf(wgt, bf2f(vd[j]), acc[8 + j]);
      }
      float rinv = 1.f / ssum;
      unsigned short od[16];
      #pragma unroll
      for (int j = 0; j < 16; j++) od[j] = f2bf(acc[j] * rinv);
      unsigned short* op = s_out + (pl0 + 32 * t) * 204 + n * 16;
      *(uint4*)(op)     = *(uint4*)&od[0];
      *(uint4*)(op + 8) = *(uint4*)&od[8];
    }
  }
  __syncthreads();

  // ---- proj phase: (64x192 bf16 LDS) x Wp^T + bp -> Out fp32, 6 waves ----
  // wave w: row half wr=w&1 (rows 32*wr..+31, 2 row-groups), nt = (w>>1)*4+t4
  const int lane = tid & 63, w = tid >> 6;
  const int wr = w & 1, wh = w >> 1;
  const int col  = lane & 15;
  const int koff = (lane >> 4) * 8;

  bf16x8 af[2][6];
  #pragma unroll
  for (int rg = 0; rg < 2; rg++) {
    int arow = 32 * wr + 16 * rg + (lane & 15);
    #pragma unroll
    for (int kt = 0; kt < 6; kt++)
      af[rg][kt] = *(const bf16x8*)&s_out[arow * 204 + koff + kt * 32];
  }

  #pragma unroll
  for (int t4 = 0; t4 < 4; t4++) {
    int nt = wh * 4 + t4;
    const unsigned short* wrow = wp + (size_t)(nt * 16 + col) * 192 + koff;
    bf16x8 bw[6];
    #pragma unroll
    for (int kt = 0; kt < 6; kt++) bw[kt] = *(const bf16x8*)(wrow + kt * 32);
    asm volatile("" ::: "memory");

    int u = nt * 16 + col;
    float bias = bp[u];
    #pragma unroll
    for (int rg = 0; rg < 2; rg++) {
      f32x4 acc = {0.f, 0.f, 0.f, 0.f};
      #pragma unroll
      for (int kt = 0; kt < 6; kt++)
        acc = __builtin_amdgcn_mfma_f32_16x16x32_bf16(af[rg][kt], bw[kt], acc, 0, 0, 0);
      int rbase = bl0 + 32 * wr + 16 * rg + 4 * (lane >> 4);
      #pragma unroll
      for (int i = 0; i < 4; i++)
        Out[(size_t)(rbase + i) * 192 + u] = acc[i] + bias;
    }
  }
}

extern "C" void kernel_launch(void* const* d_in, const int* in_sizes, int n_in,
                              void* d_out, int out_size, void* d_ws, size_t ws_size,
                              hipStream_t stream) {
  const float* x   = (const float*)d_in[0];
  const float* Wq  = (const float*)d_in[1];
  const float* bq  = (const float*)d_in[2];
  const float* Wkv = (const float*)d_in[3];
  const float* bkv = (const float*)d_in[4];
  const float* Wp  = (const float*)d_in[5];
  const float* bp  = (const float*)d_in[6];
  const float* fqr = (const float*)d_in[7];
  const float* fkr = (const float*)d_in[8];
  const float* fvr = (const float*)d_in[9];

  char* ws = (char*)d_ws;
  unsigned short* Qb   = (unsigned short*)ws;                 // 14,155,776 B
  unsigned short* KVb  = (unsigned short*)(ws + 14155776);    // 28,311,552 B
  unsigned short* wqb  = (unsigned short*)(ws + 42467328);
  unsigned short* wkvb = (unsigned short*)(ws + 42485760);
  unsigned short* wpb  = (unsigned short*)(ws + 42522624);

  cvt_w_kernel<<<dim3(252), dim3(256), 0, stream>>>(Wq, Wkv, Wp, wqb, wkvb, wpb);

  qkv_gemm<<<dim3(576), dim3(256), 0, stream>>>(
      x, wqb, wkvb, bq, bkv, fqr, fkr, fvr, Qb, KVb);

  attnproj_kernel<<<dim3(576), dim3(384), 0, stream>>>(
      Qb, KVb, wpb, bp, (float*)d_out);
}

// Round 13
// 64.911 us; speedup vs baseline: 1.2509x; 1.0198x over previous
//
#include <hip/hip_runtime.h>

#define HW2   96
#define NH    12
#define LPIX  (HW2*HW2)      // 9216
#define BATCH 4

typedef __attribute__((ext_vector_type(8))) short bf16x8;
typedef __attribute__((ext_vector_type(4))) float f32x4;

static __device__ __forceinline__ float bf2f(unsigned short u) {
  union { unsigned int i; float f; } v; v.i = ((unsigned int)u) << 16; return v.f;
}
static __device__ __forceinline__ unsigned short f2bf(float f) {
  union { float f; unsigned int i; } v; v.f = f;
  unsigned int r = v.i + 0x7FFF + ((v.i >> 16) & 1);   // round-nearest-even
  return (unsigned short)(r >> 16);
}

// ---- tiny: convert the three weight matrices to bf16 ----------------------
__global__ __launch_bounds__(256) void cvt_w_kernel(
    const float* __restrict__ Wq, const float* __restrict__ Wkv,
    const float* __restrict__ Wp,
    unsigned short* __restrict__ wqb, unsigned short* __restrict__ wkvb,
    unsigned short* __restrict__ wpb) {
  int i = blockIdx.x * 256 + threadIdx.x;
  if (i < 9216)       wqb[i]          = f2bf(Wq[i]);
  else if (i < 27648) wkvb[i - 9216]  = f2bf(Wkv[i - 9216]);
  else if (i < 64512) wpb[i - 27648]  = f2bf(Wp[i - 27648]);
}

// ---- fused Q+KV GEMM, barrier-free, ILP=2 (round-12 version, verbatim) ----
__global__ __launch_bounds__(256) void qkv_gemm(
    const float* __restrict__ X,
    const unsigned short* __restrict__ wq, const unsigned short* __restrict__ wkv,
    const float* __restrict__ bq, const float* __restrict__ bkv,
    const float* __restrict__ fqr, const float* __restrict__ fkr,
    const float* __restrict__ fvr,
    unsigned short* __restrict__ Qb, unsigned short* __restrict__ KVb)
{
  const int tid  = threadIdx.x;
  const int r0   = blockIdx.x * 128;
  const int lane = tid & 63, w = tid >> 6;
  const int col  = lane & 15;
  const int koff = (lane >> 4) * 8;
  const int arow0 = r0 + 16 * w + (lane & 15);
  const int rb0   = r0 + 16 * w + 4 * (lane >> 4);

  bf16x8 af[2][3];
  #pragma unroll
  for (int t = 0; t < 2; t++) {
    const float* xr = X + (size_t)(arow0 + 64 * t) * 96;
    float xv[24];
    *(float4*)&xv[0]  = *(const float4*)(xr + koff);
    *(float4*)&xv[4]  = *(const float4*)(xr + koff + 4);
    *(float4*)&xv[8]  = *(const float4*)(xr + koff + 32);
    *(float4*)&xv[12] = *(const float4*)(xr + koff + 36);
    *(float4*)&xv[16] = *(const float4*)(xr + koff + 64);
    *(float4*)&xv[20] = *(const float4*)(xr + koff + 68);
    unsigned short au[24];
    #pragma unroll
    for (int j = 0; j < 24; j++) au[j] = f2bf(xv[j]);
    af[t][0] = *(const bf16x8*)&au[0];
    af[t][1] = *(const bf16x8*)&au[8];
    af[t][2] = *(const bf16x8*)&au[16];
  }

  const float fqr0 = fqr[0] * 0.07216878364870322f;
  const float fkr0 = fkr[0], fvr0 = fvr[0];

  #pragma unroll
  for (int g = 0; g < 6; g++) {
    bf16x8 bw0[3], bw1[3], bw2[3];
    #pragma unroll
    for (int j = 0; j < 3; j++) {
      int nt = g * 3 + j;
      const unsigned short* wrow = (nt < 6)
          ? wq  + (size_t)(nt * 16 + col) * 96 + koff
          : wkv + (size_t)((nt - 6) * 16 + col) * 96 + koff;
      bw0[j] = *(const bf16x8*)(wrow);
      bw1[j] = *(const bf16x8*)(wrow + 32);
      bw2[j] = *(const bf16x8*)(wrow + 64);
    }
    asm volatile("" ::: "memory");

    #pragma unroll
    for (int j = 0; j < 3; j++) {
      int nt = g * 3 + j;
      f32x4 acc[2];
      #pragma unroll
      for (int t = 0; t < 2; t++) {
        f32x4 a = {0.f, 0.f, 0.f, 0.f};
        a = __builtin_amdgcn_mfma_f32_16x16x32_bf16(af[t][0], bw0[j], a, 0, 0, 0);
        a = __builtin_amdgcn_mfma_f32_16x16x32_bf16(af[t][1], bw1[j], a, 0, 0, 0);
        a = __builtin_amdgcn_mfma_f32_16x16x32_bf16(af[t][2], bw2[j], a, 0, 0, 0);
        acc[t] = a;
      }

      if (nt < 6) {
        int u = nt * 16 + col;
        float bias = bq[u];
        #pragma unroll
        for (int t = 0; t < 2; t++)
          #pragma unroll
          for (int i = 0; i < 4; i++)
            Qb[(size_t)(rb0 + 64 * t + i) * 96 + u] = f2bf((acc[t][i] + bias) * fqr0);
      } else {
        int u = (nt - 6) * 16 + col;
        float bias = bkv[u];
        #pragma unroll
        for (int t = 0; t < 2; t++)
          #pragma unroll
          for (int i = 0; i < 4; i++) {
            float s = (i & 1) ? fvr0 : fkr0;   // row parity: even=K, odd=V
            KVb[(size_t)(rb0 + 64 * t + i) * 192 + u] = f2bf((acc[t][i] + bias) * s);
          }
      }
    }
  }
}

// ---- fused attention + proj: thread = (head, PIXEL PAIR); the pair shares
// its 3x4 K/V halo -> 12 loads per phase instead of 18 for the same 2 tasks.
__global__ __launch_bounds__(384) void attnproj_kernel(
    const unsigned short* __restrict__ Qb, const unsigned short* __restrict__ KVb,
    const unsigned short* __restrict__ wp, const float* __restrict__ bp,
    float* __restrict__ Out)
{
  __shared__ unsigned short s_out[64 * 204];
  const int tid = threadIdx.x;
  // XCD-chunked swizzle (576 blocks, 72/XCD): halo rows share an XCD L2.
  const int bid = (blockIdx.x & 7) * 72 + (blockIdx.x >> 3);
  const int bl0 = bid * 64;

  {
    const int n  = tid % NH;
    const int pp = tid / NH;                   // pixel pair 0..31
    const int b  = bl0 / LPIX;                 // block never straddles batch
    const int l0 = (bl0 % LPIX) + 2 * pp;      // even; pair = (l0, l0+1)
    const int h2 = l0 / HW2, w2 = l0 - h2 * HW2;   // w2 even, <= 94

    const unsigned short* kvb = KVb + (size_t)b * (LPIX * 384) + n * 16;

    // ---- shared 3x4 halo: offsets + clamp (pure VALU) ----
    int nbo[12];
    #pragma unroll
    for (int hx = 0; hx < 12; hx++) {
      int hh = h2 + hx / 4 - 1;
      int ww = w2 + (hx & 3) - 1;
      int hc = min(max(hh, 0), HW2 - 1);
      int wc = min(max(ww, 0), HW2 - 1);
      nbo[hx] = (hc * HW2 + wc) * 384;
    }
    const bool rok[3] = { h2 > 0, true, h2 < HW2 - 1 };
    // col validity for task t, dc in {-1,0,1}: w2+t+dc in [0,96)
    // only edges can fail: t=0,dc=-1 (w2==0) and t=1,dc=+1 (w2==94)

    // ---- batched K issue (12 halo pixels) + Q (2 tasks), then fence ----
    uint4 kH[12][2];
    #pragma unroll
    for (int hx = 0; hx < 12; hx++) {
      const unsigned short* kp = kvb + nbo[hx];
      kH[hx][0] = *(const uint4*)(kp);
      kH[hx][1] = *(const uint4*)(kp + 8);
    }
    uint4 qA[2], qB[2];
    #pragma unroll
    for (int t = 0; t < 2; t++) {
      const unsigned short* qp = Qb + (size_t)(b * LPIX + l0 + t) * 192 + n * 16;
      qA[t] = *(const uint4*)(qp);
      qB[t] = *(const uint4*)(qp + 8);
    }
    asm volatile("" ::: "memory");

    // ---- scores for both tasks from the shared halo ----
    float q[2][16];
    #pragma unroll
    for (int t = 0; t < 2; t++) {
      const unsigned short* qs = (const unsigned short*)&qA[t];
      #pragma unroll
      for (int j = 0; j < 8; j++) q[t][j] = bf2f(qs[j]);
      qs = (const unsigned short*)&qB[t];
      #pragma unroll
      for (int j = 0; j < 8; j++) q[t][8 + j] = bf2f(qs[j]);
    }

    float sc[2][9];
    bool  okk[2][9];
    #pragma unroll
    for (int t = 0; t < 2; t++) {
      #pragma unroll
      for (int kk = 0; kk < 9; kk++) {
        int dr = kk / 3, dc = kk % 3;          // 0..2 each
        int hx = dr * 4 + dc + t;              // shared halo index
        int wcol = w2 + t + dc - 1;
        okk[t][kk] = rok[dr] && ((unsigned)wcol < (unsigned)HW2);
        float s = 0.f;
        const unsigned short* kd = (const unsigned short*)&kH[hx][0];
        #pragma unroll
        for (int j = 0; j < 8; j++) s = fmaf(q[t][j], bf2f(kd[j]), s);
        kd = (const unsigned short*)&kH[hx][1];
        #pragma unroll
        for (int j = 0; j < 8; j++) s = fmaf(q[t][8 + j], bf2f(kd[j]), s);
        sc[t][kk] = okk[t][kk] ? s : 0.f;
      }
    }

    // ---- batched V issue (12 halo pixels), then fence ----
    uint4 vH[12][2];
    #pragma unroll
    for (int hx = 0; hx < 12; hx++) {
      const unsigned short* vp = kvb + nbo[hx] + 192;
      vH[hx][0] = *(const uint4*)(vp);
      vH[hx][1] = *(const uint4*)(vp + 8);
    }
    asm volatile("" ::: "memory");

    // ---- softmax + PV + LDS store per task ----
    #pragma unroll
    for (int t = 0; t < 2; t++) {
      float m = sc[t][0];
      #pragma unroll
      for (int kk = 1; kk < 9; kk++) m = fmaxf(m, sc[t][kk]);
      float ssum = 0.f;
      #pragma unroll
      for (int kk = 0; kk < 9; kk++) {
        float e = __expf(sc[t][kk] - m);
        sc[t][kk] = e;
        ssum += e;
      }
      float acc[16];
      #pragma unroll
      for (int j = 0; j < 16; j++) acc[j] = 0.f;
      #pragma unroll
      for (int kk = 0; kk < 9; kk++) {
        int hx = (kk / 3) * 4 + (kk % 3) + t;
        float wgt = okk[t][kk] ? sc[t][kk] : 0.f;
        const unsigned short* vd = (const unsigned short*)&vH[hx][0];
        #pragma unroll
        for (int j = 0; j < 8; j++) acc[j] = fmaf(wgt, bf2f(vd[j]), acc[j]);
        vd = (const unsigned short*)&vH[hx][1];
        #pragma unroll
        for (int j = 0; j < 8; j++) acc[8 + j] = fmaf(wgt, bf2f(vd[j]), acc[8 + j]);
      }
      float rinv = 1.f / ssum;
      unsigned short od[16];
      #pragma unroll
      for (int j = 0; j < 16; j++) od[j] = f2bf(acc[j] * rinv);
      unsigned short* op = s_out + (2 * pp + t) * 204 + n * 16;
      *(uint4*)(op)     = *(uint4*)&od[0];
      *(uint4*)(op + 8) = *(uint4*)&od[8];
    }
  }
  __syncthreads();

  // ---- proj phase: (64x192 bf16 LDS) x Wp^T + bp -> Out fp32, 6 waves ----
  const int lane = tid & 63, w = tid >> 6;
  const int wr = w & 1, wh = w >> 1;
  const int col  = lane & 15;
  const int koff = (lane >> 4) * 8;

  bf16x8 af[2][6];
  #pragma unroll
  for (int rg = 0; rg < 2; rg++) {
    int arow = 32 * wr + 16 * rg + (lane & 15);
    #pragma unroll
    for (int kt = 0; kt < 6; kt++)
      af[rg][kt] = *(const bf16x8*)&s_out[arow * 204 + koff + kt * 32];
  }

  #pragma unroll
  for (int t4 = 0; t4 < 4; t4++) {
    int nt = wh * 4 + t4;
    const unsigned short* wrow = wp + (size_t)(nt * 16 + col) * 192 + koff;
    bf16x8 bw[6];
    #pragma unroll
    for (int kt = 0; kt < 6; kt++) bw[kt] = *(const bf16x8*)(wrow + kt * 32);
    asm volatile("" ::: "memory");

    int u = nt * 16 + col;
    float bias = bp[u];
    #pragma unroll
    for (int rg = 0; rg < 2; rg++) {
      f32x4 acc = {0.f, 0.f, 0.f, 0.f};
      #pragma unroll
      for (int kt = 0; kt < 6; kt++)
        acc = __builtin_amdgcn_mfma_f32_16x16x32_bf16(af[rg][kt], bw[kt], acc, 0, 0, 0);
      int rbase = bl0 + 32 * wr + 16 * rg + 4 * (lane >> 4);
      #pragma unroll
      for (int i = 0; i < 4; i++)
        Out[(size_t)(rbase + i) * 192 + u] = acc[i] + bias;
    }
  }
}

extern "C" void kernel_launch(void* const* d_in, const int* in_sizes, int n_in,
                              void* d_out, int out_size, void* d_ws, size_t ws_size,
                              hipStream_t stream) {
  const float* x   = (const float*)d_in[0];
  const float* Wq  = (const float*)d_in[1];
  const float* bq  = (const float*)d_in[2];
  const float* Wkv = (const float*)d_in[3];
  const float* bkv = (const float*)d_in[4];
  const float* Wp  = (const float*)d_in[5];
  const float* bp  = (const float*)d_in[6];
  const float* fqr = (const float*)d_in[7];
  const float* fkr = (const float*)d_in[8];
  const float* fvr = (const float*)d_in[9];

  char* ws = (char*)d_ws;
  unsigned short* Qb   = (unsigned short*)ws;                 // 14,155,776 B
  unsigned short* KVb  = (unsigned short*)(ws + 14155776);    // 28,311,552 B
  unsigned short* wqb  = (unsigned short*)(ws + 42467328);
  unsigned short* wkvb = (unsigned short*)(ws + 42485760);
  unsigned short* wpb  = (unsigned short*)(ws + 42522624);

  cvt_w_kernel<<<dim3(252), dim3(256), 0, stream>>>(Wq, Wkv, Wp, wqb, wkvb, wpb);

  qkv_gemm<<<dim3(576), dim3(256), 0, stream>>>(
      x, wqb, wkvb, bq, bkv, fqr, fkr, fvr, Qb, KVb);

  attnproj_kernel<<<dim3(576), dim3(384), 0, stream>>>(
      Qb, KVb, wpb, bp, (float*)d_out);
}

// Round 14
// 63.820 us; speedup vs baseline: 1.2722x; 1.0171x over previous
//
#include <hip/hip_runtime.h>

#define HW2   96
#define NH    12
#define LPIX  (HW2*HW2)      // 9216
#define BATCH 4

typedef __attribute__((ext_vector_type(8))) short bf16x8;
typedef __attribute__((ext_vector_type(4))) float f32x4;

static __device__ __forceinline__ float bf2f(unsigned short u) {
  union { unsigned int i; float f; } v; v.i = ((unsigned int)u) << 16; return v.f;
}
static __device__ __forceinline__ unsigned short f2bf(float f) {
  union { float f; unsigned int i; } v; v.f = f;
  unsigned int r = v.i + 0x7FFF + ((v.i >> 16) & 1);   // round-nearest-even
  return (unsigned short)(r >> 16);
}

// ---- tiny: convert the three weight matrices to bf16 ----------------------
__global__ __launch_bounds__(256) void cvt_w_kernel(
    const float* __restrict__ Wq, const float* __restrict__ Wkv,
    const float* __restrict__ Wp,
    unsigned short* __restrict__ wqb, unsigned short* __restrict__ wkvb,
    unsigned short* __restrict__ wpb) {
  int i = blockIdx.x * 256 + threadIdx.x;
  if (i < 9216)       wqb[i]          = f2bf(Wq[i]);
  else if (i < 27648) wkvb[i - 9216]  = f2bf(Wkv[i - 9216]);
  else if (i < 64512) wpb[i - 27648]  = f2bf(Wp[i - 27648]);
}

// ---- fused Q+KV GEMM, barrier-free, ILP=2 (round-12 version, verbatim) ----
__global__ __launch_bounds__(256) void qkv_gemm(
    const float* __restrict__ X,
    const unsigned short* __restrict__ wq, const unsigned short* __restrict__ wkv,
    const float* __restrict__ bq, const float* __restrict__ bkv,
    const float* __restrict__ fqr, const float* __restrict__ fkr,
    const float* __restrict__ fvr,
    unsigned short* __restrict__ Qb, unsigned short* __restrict__ KVb)
{
  const int tid  = threadIdx.x;
  const int r0   = blockIdx.x * 128;
  const int lane = tid & 63, w = tid >> 6;
  const int col  = lane & 15;
  const int koff = (lane >> 4) * 8;
  const int arow0 = r0 + 16 * w + (lane & 15);
  const int rb0   = r0 + 16 * w + 4 * (lane >> 4);

  bf16x8 af[2][3];
  #pragma unroll
  for (int t = 0; t < 2; t++) {
    const float* xr = X + (size_t)(arow0 + 64 * t) * 96;
    float xv[24];
    *(float4*)&xv[0]  = *(const float4*)(xr + koff);
    *(float4*)&xv[4]  = *(const float4*)(xr + koff + 4);
    *(float4*)&xv[8]  = *(const float4*)(xr + koff + 32);
    *(float4*)&xv[12] = *(const float4*)(xr + koff + 36);
    *(float4*)&xv[16] = *(const float4*)(xr + koff + 64);
    *(float4*)&xv[20] = *(const float4*)(xr + koff + 68);
    unsigned short au[24];
    #pragma unroll
    for (int j = 0; j < 24; j++) au[j] = f2bf(xv[j]);
    af[t][0] = *(const bf16x8*)&au[0];
    af[t][1] = *(const bf16x8*)&au[8];
    af[t][2] = *(const bf16x8*)&au[16];
  }

  const float fqr0 = fqr[0] * 0.07216878364870322f;
  const float fkr0 = fkr[0], fvr0 = fvr[0];

  #pragma unroll
  for (int g = 0; g < 6; g++) {
    bf16x8 bw0[3], bw1[3], bw2[3];
    #pragma unroll
    for (int j = 0; j < 3; j++) {
      int nt = g * 3 + j;
      const unsigned short* wrow = (nt < 6)
          ? wq  + (size_t)(nt * 16 + col) * 96 + koff
          : wkv + (size_t)((nt - 6) * 16 + col) * 96 + koff;
      bw0[j] = *(const bf16x8*)(wrow);
      bw1[j] = *(const bf16x8*)(wrow + 32);
      bw2[j] = *(const bf16x8*)(wrow + 64);
    }
    asm volatile("" ::: "memory");

    #pragma unroll
    for (int j = 0; j < 3; j++) {
      int nt = g * 3 + j;
      f32x4 acc[2];
      #pragma unroll
      for (int t = 0; t < 2; t++) {
        f32x4 a = {0.f, 0.f, 0.f, 0.f};
        a = __builtin_amdgcn_mfma_f32_16x16x32_bf16(af[t][0], bw0[j], a, 0, 0, 0);
        a = __builtin_amdgcn_mfma_f32_16x16x32_bf16(af[t][1], bw1[j], a, 0, 0, 0);
        a = __builtin_amdgcn_mfma_f32_16x16x32_bf16(af[t][2], bw2[j], a, 0, 0, 0);
        acc[t] = a;
      }

      if (nt < 6) {
        int u = nt * 16 + col;
        float bias = bq[u];
        #pragma unroll
        for (int t = 0; t < 2; t++)
          #pragma unroll
          for (int i = 0; i < 4; i++)
            Qb[(size_t)(rb0 + 64 * t + i) * 96 + u] = f2bf((acc[t][i] + bias) * fqr0);
      } else {
        int u = (nt - 6) * 16 + col;
        float bias = bkv[u];
        #pragma unroll
        for (int t = 0; t < 2; t++)
          #pragma unroll
          for (int i = 0; i < 4; i++) {
            float s = (i & 1) ? fvr0 : fkr0;   // row parity: even=K, odd=V
            KVb[(size_t)(rb0 + 64 * t + i) * 192 + u] = f2bf((acc[t][i] + bias) * s);
          }
      }
    }
  }
}

// ---- fused attention + proj: thread = (head, 2x2 PIXEL QUAD); the quad
// shares a 4x4 K/V halo -> 16 loads/phase for 4 tasks (R13: 12 for 2).
// Block = 2 image rows x 32 cols = 64 pixels, 192 threads.
__global__ __launch_bounds__(192, 1) void attnproj_kernel(
    const unsigned short* __restrict__ Qb, const unsigned short* __restrict__ KVb,
    const unsigned short* __restrict__ wp, const float* __restrict__ bp,
    float* __restrict__ Out)
{
  __shared__ unsigned short s_out[64 * 204];
  const int tid = threadIdx.x;
  // XCD-chunked swizzle (576 blocks = 8 x 72, bijective)
  const int bid = (blockIdx.x & 7) * 72 + (blockIdx.x >> 3);
  const int b   = bid / 144;
  const int rem = bid % 144;
  const int hp  = rem / 3, wt = rem % 3;
  const int h   = 2 * hp;                     // even, 0..94
  const int w0  = 32 * wt;

  {
    const int n  = tid % NH;
    const int qd = tid / NH;                  // quad 0..15
    const int w  = w0 + 2 * qd;               // even, <= 94

    const unsigned short* kvb = KVb + (size_t)b * (LPIX * 384) + n * 16;

    // ---- shared 4x4 halo offsets (clamped; validity applied later) ----
    int nbo[16];
    #pragma unroll
    for (int hx = 0; hx < 16; hx++) {
      int hh = h + (hx >> 2) - 1;
      int ww = w + (hx & 3) - 1;
      int hc = min(max(hh, 0), HW2 - 1);
      int wc = min(max(ww, 0), HW2 - 1);
      nbo[hx] = (hc * HW2 + wc) * 384;
    }
    const bool rok[4] = { h > 0, true, true, h < HW2 - 2 };

    // ---- batched K (16 halo px) + Q (4 tasks) issue, then fence ----
    uint4 kH[16][2];
    #pragma unroll
    for (int hx = 0; hx < 16; hx++) {
      const unsigned short* kp = kvb + nbo[hx];
      kH[hx][0] = *(const uint4*)(kp);
      kH[hx][1] = *(const uint4*)(kp + 8);
    }
    uint4 qA[4], qB[4];
    #pragma unroll
    for (int t = 0; t < 4; t++) {
      int l = (h + (t >> 1)) * HW2 + w + (t & 1);
      const unsigned short* qp = Qb + ((size_t)b * LPIX + l) * 192 + n * 16;
      qA[t] = *(const uint4*)(qp);
      qB[t] = *(const uint4*)(qp + 8);
    }
    asm volatile("" ::: "memory");

    // ---- scores for 4 tasks from the shared halo ----
    float sc[4][9];
    bool  okk[4][9];
    #pragma unroll
    for (int t = 0; t < 4; t++) {
      const int tr = t >> 1, tc = t & 1;
      float q[16];
      const unsigned short* qs = (const unsigned short*)&qA[t];
      #pragma unroll
      for (int j = 0; j < 8; j++) q[j] = bf2f(qs[j]);
      qs = (const unsigned short*)&qB[t];
      #pragma unroll
      for (int j = 0; j < 8; j++) q[8 + j] = bf2f(qs[j]);
      #pragma unroll
      for (int kk = 0; kk < 9; kk++) {
        int dr = kk / 3, dc = kk % 3;
        int hx = (dr + tr) * 4 + dc + tc;
        int wcol = w + tc + dc - 1;
        okk[t][kk] = rok[dr + tr] && ((unsigned)wcol < (unsigned)HW2);
        float s = 0.f;
        const unsigned short* kd = (const unsigned short*)&kH[hx][0];
        #pragma unroll
        for (int j = 0; j < 8; j++) s = fmaf(q[j], bf2f(kd[j]), s);
        kd = (const unsigned short*)&kH[hx][1];
        #pragma unroll
        for (int j = 0; j < 8; j++) s = fmaf(q[8 + j], bf2f(kd[j]), s);
        sc[t][kk] = okk[t][kk] ? s : 0.f;
      }
    }

    // ---- batched V issue (16 halo px), then fence ----
    uint4 vH[16][2];
    #pragma unroll
    for (int hx = 0; hx < 16; hx++) {
      const unsigned short* vp = kvb + nbo[hx] + 192;
      vH[hx][0] = *(const uint4*)(vp);
      vH[hx][1] = *(const uint4*)(vp + 8);
    }
    asm volatile("" ::: "memory");

    // ---- softmax + PV + LDS store per task ----
    #pragma unroll
    for (int t = 0; t < 4; t++) {
      const int tr = t >> 1, tc = t & 1;
      float m = sc[t][0];
      #pragma unroll
      for (int kk = 1; kk < 9; kk++) m = fmaxf(m, sc[t][kk]);
      float ssum = 0.f;
      #pragma unroll
      for (int kk = 0; kk < 9; kk++) {
        float e = __expf(sc[t][kk] - m);
        sc[t][kk] = e;
        ssum += e;
      }
      float acc[16];
      #pragma unroll
      for (int j = 0; j < 16; j++) acc[j] = 0.f;
      #pragma unroll
      for (int kk = 0; kk < 9; kk++) {
        int hx = (kk / 3 + tr) * 4 + kk % 3 + tc;
        float wgt = okk[t][kk] ? sc[t][kk] : 0.f;
        const unsigned short* vd = (const unsigned short*)&vH[hx][0];
        #pragma unroll
        for (int j = 0; j < 8; j++) acc[j] = fmaf(wgt, bf2f(vd[j]), acc[j]);
        vd = (const unsigned short*)&vH[hx][1];
        #pragma unroll
        for (int j = 0; j < 8; j++) acc[8 + j] = fmaf(wgt, bf2f(vd[j]), acc[8 + j]);
      }
      float rinv = 1.f / ssum;
      unsigned short od[16];
      #pragma unroll
      for (int j = 0; j < 16; j++) od[j] = f2bf(acc[j] * rinv);
      int sr = tr * 32 + 2 * qd + tc;          // s_out row: strip*32 + wl
      unsigned short* op = s_out + sr * 204 + n * 16;
      *(uint4*)(op)     = *(uint4*)&od[0];
      *(uint4*)(op + 8) = *(uint4*)&od[8];
    }
  }
  __syncthreads();

  // ---- proj: (64x192 LDS) x Wp^T + bp -> Out fp32. 3 waves x 4 nt each;
  // each wave covers all 64 rows (4 row-groups).
  const int lane = tid & 63, wv = tid >> 6;    // wv 0..2
  const int col  = lane & 15;
  const int koff = (lane >> 4) * 8;

  bf16x8 af[4][6];
  #pragma unroll
  for (int rg = 0; rg < 4; rg++) {
    int arow = 16 * rg + (lane & 15);
    #pragma unroll
    for (int kt = 0; kt < 6; kt++)
      af[rg][kt] = *(const bf16x8*)&s_out[arow * 204 + koff + kt * 32];
  }

  #pragma unroll
  for (int t4 = 0; t4 < 4; t4++) {
    int nt = wv * 4 + t4;
    const unsigned short* wrow = wp + (size_t)(nt * 16 + col) * 192 + koff;
    bf16x8 bw[6];
    #pragma unroll
    for (int kt = 0; kt < 6; kt++) bw[kt] = *(const bf16x8*)(wrow + kt * 32);
    asm volatile("" ::: "memory");

    int u = nt * 16 + col;
    float bias = bp[u];
    #pragma unroll
    for (int rg = 0; rg < 4; rg++) {
      f32x4 acc = {0.f, 0.f, 0.f, 0.f};
      #pragma unroll
      for (int kt = 0; kt < 6; kt++)
        acc = __builtin_amdgcn_mfma_f32_16x16x32_bf16(af[rg][kt], bw[kt], acc, 0, 0, 0);
      // s_out row -> global pixel: strip = rg>>1, wl = 16*(rg&1)+4*(lane>>4)+i
      int hh_out = h + (rg >> 1);
      int wbase  = w0 + 16 * (rg & 1) + 4 * (lane >> 4);
      #pragma unroll
      for (int i = 0; i < 4; i++) {
        int row_g = b * LPIX + hh_out * HW2 + wbase + i;
        Out[(size_t)row_g * 192 + u] = acc[i] + bias;
      }
    }
  }
}

extern "C" void kernel_launch(void* const* d_in, const int* in_sizes, int n_in,
                              void* d_out, int out_size, void* d_ws, size_t ws_size,
                              hipStream_t stream) {
  const float* x   = (const float*)d_in[0];
  const float* Wq  = (const float*)d_in[1];
  const float* bq  = (const float*)d_in[2];
  const float* Wkv = (const float*)d_in[3];
  const float* bkv = (const float*)d_in[4];
  const float* Wp  = (const float*)d_in[5];
  const float* bp  = (const float*)d_in[6];
  const float* fqr = (const float*)d_in[7];
  const float* fkr = (const float*)d_in[8];
  const float* fvr = (const float*)d_in[9];

  char* ws = (char*)d_ws;
  unsigned short* Qb   = (unsigned short*)ws;                 // 14,155,776 B
  unsigned short* KVb  = (unsigned short*)(ws + 14155776);    // 28,311,552 B
  unsigned short* wqb  = (unsigned short*)(ws + 42467328);
  unsigned short* wkvb = (unsigned short*)(ws + 42485760);
  unsigned short* wpb  = (unsigned short*)(ws + 42522624);

  cvt_w_kernel<<<dim3(252), dim3(256), 0, stream>>>(Wq, Wkv, Wp, wqb, wkvb, wpb);

  qkv_gemm<<<dim3(576), dim3(256), 0, stream>>>(
      x, wqb, wkvb, bq, bkv, fqr, fkr, fvr, Qb, KVb);

  attnproj_kernel<<<dim3(576), dim3(192), 0, stream>>>(
      Qb, KVb, wpb, bp, (float*)d_out);
}